// Round 1
// baseline (11498.128 us; speedup 1.0000x reference)
//
#include <hip/hip_runtime.h>
#include <hip/hip_bf16.h>

// GRU-style recurrence: B=128, S=512, H=1024, fp32 in/out.
// Strategy (round 1): per-step kernels, bf16 MFMA GEMMs with fp32 accum.
//   stage1: [128 x 2048] = sigmoid(p_xi @ [Ww|Uw]^T + [Wb|Ub])
//           -> writes a_v = r*p + x (bf16) and z (fp32)
//   stage2: h = tanh(a_v @ Vw^T + Vb); p = (1-z)p + z h; out[:,t,:] = p;
//           also writes p_xi(t+1) = bf16(x_{t+1} + p)
// Weights converted to bf16 once per launch. p carried in fp32 across steps.

#define Bb 128
#define Ss 512
#define Hh 1024

typedef __bf16 bf16x8 __attribute__((ext_vector_type(8)));
typedef float f32x4 __attribute__((ext_vector_type(4)));

__device__ __forceinline__ float sigmoid_fast(float x) {
    return 1.0f / (1.0f + __expf(-x));
}
__device__ __forceinline__ float tanh_fast(float x) {
    return 2.0f / (1.0f + __expf(-2.0f * x)) - 1.0f;
}

// ---- one-time init kernels -------------------------------------------------

__global__ __launch_bounds__(256) void k_init_weights(
    const float* __restrict__ Ww, const float* __restrict__ Uw,
    const float* __restrict__ Vw,
    __bf16* __restrict__ WU, __bf16* __restrict__ Vbf)
{
    int i = blockIdx.x * 256 + threadIdx.x;   // grid covers H*H
    WU[i]            = (__bf16)Ww[i];
    WU[Hh * Hh + i]  = (__bf16)Uw[i];
    Vbf[i]           = (__bf16)Vw[i];
}

__global__ __launch_bounds__(256) void k_init_state(
    const float* __restrict__ emb, float* __restrict__ p, __bf16* __restrict__ pxi)
{
    int i = blockIdx.x * 256 + threadIdx.x;   // grid covers B*H
    p[i] = 0.0f;
    int b = i >> 10;
    int j = i & 1023;
    // p0 = 0  =>  p_xi(0) = x_0
    pxi[i] = (__bf16)emb[(size_t)b * (Ss * Hh) + j];
}

// ---- stage 1: r,z GEMM [128 x 2048 x 1024] --------------------------------
// grid 256 blocks x 256 thr = 1024 waves; wave w owns 16x16 tile
//   m0 = (w>>7)*16 (8 groups over B=128), n0 = (w&127)*16 (128 over N=2048)

__global__ __launch_bounds__(256) void k_stage1(
    const __bf16* __restrict__ pxi, const __bf16* __restrict__ WU,
    const float* __restrict__ Wb, const float* __restrict__ Ub,
    const float* __restrict__ p, const float* __restrict__ emb, int t,
    __bf16* __restrict__ av, float* __restrict__ z)
{
    int lane = threadIdx.x & 63;
    int wid  = threadIdx.x >> 6;
    int w    = blockIdx.x * 4 + wid;          // 0..1023
    int m0   = (w >> 7) << 4;
    int n0   = (w & 127) << 4;
    int la   = lane & 15, lb = lane >> 4;

    const __bf16* ap = pxi + (size_t)(m0 + la) * Hh + lb * 8;
    const __bf16* bp = WU  + (size_t)(n0 + la) * Hh + lb * 8;

    f32x4 acc = {0.f, 0.f, 0.f, 0.f};
#pragma unroll 4
    for (int k = 0; k < Hh; k += 32) {
        bf16x8 a = *reinterpret_cast<const bf16x8*>(ap + k);
        bf16x8 b = *reinterpret_cast<const bf16x8*>(bp + k);
        acc = __builtin_amdgcn_mfma_f32_16x16x32_bf16(a, b, acc, 0, 0, 0);
    }

    int j = n0 + la;                          // wave-uniform branch (n0 uniform)
    if (j < Hh) {                             // r-part
        float bias = Wb[j];
#pragma unroll
        for (int r = 0; r < 4; ++r) {
            int brow = m0 + lb * 4 + r;
            float rg = sigmoid_fast(acc[r] + bias);
            float pv = p[brow * Hh + j];
            float xv = emb[(size_t)brow * (Ss * Hh) + (size_t)t * Hh + j];
            av[brow * Hh + j] = (__bf16)(rg * pv + xv);
        }
    } else {                                  // z-part
        int jj = j - Hh;
        float bias = Ub[jj];
#pragma unroll
        for (int r = 0; r < 4; ++r) {
            int brow = m0 + lb * 4 + r;
            z[brow * Hh + jj] = sigmoid_fast(acc[r] + bias);
        }
    }
}

// ---- stage 2: h GEMM [128 x 1024 x 1024] + gate combine --------------------
// grid 128 blocks = 512 waves; m0 = (w>>6)*16, n0 = (w&63)*16

__global__ __launch_bounds__(256) void k_stage2(
    const __bf16* __restrict__ av, const __bf16* __restrict__ Vm,
    const float* __restrict__ Vb, const float* __restrict__ zbuf,
    float* __restrict__ p, const float* __restrict__ emb, int t,
    float* __restrict__ out, __bf16* __restrict__ pxi)
{
    int lane = threadIdx.x & 63;
    int wid  = threadIdx.x >> 6;
    int w    = blockIdx.x * 4 + wid;          // 0..511
    int m0   = (w >> 6) << 4;
    int n0   = (w & 63) << 4;
    int la   = lane & 15, lb = lane >> 4;

    const __bf16* ap = av + (size_t)(m0 + la) * Hh + lb * 8;
    const __bf16* bp = Vm + (size_t)(n0 + la) * Hh + lb * 8;

    f32x4 acc = {0.f, 0.f, 0.f, 0.f};
#pragma unroll 4
    for (int k = 0; k < Hh; k += 32) {
        bf16x8 a = *reinterpret_cast<const bf16x8*>(ap + k);
        bf16x8 b = *reinterpret_cast<const bf16x8*>(bp + k);
        acc = __builtin_amdgcn_mfma_f32_16x16x32_bf16(a, b, acc, 0, 0, 0);
    }

    int j = n0 + la;
    float bias = Vb[j];
#pragma unroll
    for (int r = 0; r < 4; ++r) {
        int brow = m0 + lb * 4 + r;
        float h  = tanh_fast(acc[r] + bias);
        float zz = zbuf[brow * Hh + j];
        float pn = (1.0f - zz) * p[brow * Hh + j] + zz * h;
        p[brow * Hh + j] = pn;
        out[(size_t)brow * (Ss * Hh) + (size_t)t * Hh + j] = pn;
        if (t + 1 < Ss) {
            float xn = emb[(size_t)brow * (Ss * Hh) + (size_t)(t + 1) * Hh + j];
            pxi[brow * Hh + j] = (__bf16)(pn + xn);
        }
    }
}

// ---- launch -----------------------------------------------------------------

extern "C" void kernel_launch(void* const* d_in, const int* in_sizes, int n_in,
                              void* d_out, int out_size, void* d_ws, size_t ws_size,
                              hipStream_t stream) {
    const float* emb = (const float*)d_in[0];
    const float* Ww  = (const float*)d_in[1];
    const float* Wb  = (const float*)d_in[2];
    const float* Uw  = (const float*)d_in[3];
    const float* Ub  = (const float*)d_in[4];
    const float* Vw  = (const float*)d_in[5];
    const float* Vb  = (const float*)d_in[6];
    float* out = (float*)d_out;

    char* ws = (char*)d_ws;
    __bf16* WU   = (__bf16*)(ws);                                     // 4 MB  [2048][1024]
    __bf16* Vbf  = (__bf16*)(ws + (size_t)4 * 1024 * 1024);           // 2 MB  [1024][1024]
    float*  p    = (float*) (ws + (size_t)6 * 1024 * 1024);           // 512 KB [128][1024]
    float*  zbuf = (float*) (ws + (size_t)6 * 1024 * 1024 + 512*1024);// 512 KB
    __bf16* pxi  = (__bf16*)(ws + (size_t)7 * 1024 * 1024);           // 256 KB
    __bf16* av   = (__bf16*)(ws + (size_t)7 * 1024 * 1024 + 256*1024);// 256 KB

    k_init_weights<<<(Hh * Hh) / 256, 256, 0, stream>>>(Ww, Uw, Vw, WU, Vbf);
    k_init_state<<<(Bb * Hh) / 256, 256, 0, stream>>>(emb, p, pxi);

    for (int t = 0; t < Ss; ++t) {
        k_stage1<<<256, 256, 0, stream>>>(pxi, WU, Wb, Ub, p, emb, t, av, zbuf);
        k_stage2<<<128, 256, 0, stream>>>(av, Vbf, Vb, zbuf, p, emb, t, out, pxi);
    }
}